// Round 4
// baseline (84.304 us; speedup 1.0000x reference)
//
#include <hip/hip_runtime.h>
#include <hip/hip_fp16.h>

// Parallel-beam 2D forward projection (Radon), ray-driven bilinear.
// Full image in LDS as fp16 (flat): halves H[ly][lx], ly=y+1 (0..258), lx=x+2,
// row stride RW=131 dwords. Guards are zero -> no per-tap masking.
// One bilinear sample = 2x ds_read2_b32 + 2x v_alignbit + 2x cvt + lerps.
// Branchless slab clip for 16 rays in parallel across lanes (readlane
// broadcast), lanes t-major per ray, shuffle reduce, coalesced store.

#define NVOL 256
#define NANG 180
#define NDET 363

constexpr int RW        = 131;                 // dwords per row (odd: bank spread)
constexpr int NROWS     = 259;
constexpr int LDS_WORDS = NROWS * RW;          // 33929
constexpr size_t LDS_BYTES = (size_t)LDS_WORDS * 4;  // 135716 B -> 1 block/CU

constexpr int DCH = 16;                        // dets per unit
constexpr int NCH = 23;                        // ceil(363/16)
constexpr int NUB = NANG * NCH;                // 4140 units per batch

__device__ __forceinline__ float rlane_f(float v, int l) {
    return __builtin_bit_cast(float, __builtin_amdgcn_readlane(__builtin_bit_cast(int, v), l));
}

// one bilinear sample; FX,FY are local (guard-offset) coords, >= 0 by clipping
#define SAMP(FX, FY) ({                                                         \
    int ix_ = (int)(FX);  int iy_ = (int)(FY);                                  \
    float wx_ = (FX) - (float)ix_;                                              \
    float wy_ = (FY) - (float)iy_;                                              \
    const unsigned* row_ = &L[iy_ * RW + (ix_ >> 1)];                           \
    unsigned w00_ = row_[0],  w01_ = row_[1];                                   \
    unsigned w10_ = row_[RW], w11_ = row_[RW + 1];                              \
    unsigned sh_ = (unsigned)((ix_ & 1) << 4);                                  \
    unsigned p0_ = __builtin_amdgcn_alignbit(w01_, w00_, sh_);                  \
    unsigned p1_ = __builtin_amdgcn_alignbit(w11_, w10_, sh_);                  \
    float2 f0_ = __half22float2(__builtin_bit_cast(__half2, p0_));              \
    float2 f1_ = __half22float2(__builtin_bit_cast(__half2, p1_));              \
    float c0_ = fmaf(wy_, f1_.x - f0_.x, f0_.x);                                \
    float c1_ = fmaf(wy_, f1_.y - f0_.y, f0_.y);                                \
    fmaf(wx_, c1_ - c0_, c0_); })

__global__ __launch_bounds__(1024, 4)
void proj_kernel(const float* __restrict__ img, float* __restrict__ out,
                 unsigned* __restrict__ cnt)
{
    extern __shared__ unsigned L[];
    const int tid   = threadIdx.x;
    const int batch = blockIdx.x & 1;

    // zero LDS (guards + pads)
    for (int i = tid; i < LDS_WORDS; i += 1024) L[i] = 0u;
    __syncthreads();

    // stage image rows 0..255 -> ly=1..256, cols x -> lx=x+2
    const float4* img4 = (const float4*)(img + batch * (NVOL * NVOL));
    __half2* Lh2 = (__half2*)L;
    #pragma unroll
    for (int it = 0; it < 16; ++it) {
        int g = tid + (it << 10);
        int r = g >> 6, q = g & 63;            // row 0..255, float4 index 0..63
        float4 v = img4[g];
        int w = (r + 1) * RW + (q << 1) + 1;   // halves lx = 4q+2 .. 4q+5
        Lh2[w]     = __floats2half2_rn(v.x, v.y);
        Lh2[w + 1] = __floats2half2_rn(v.z, v.w);
    }
    __syncthreads();

    const int lane = tid & 63;
    unsigned* ctr  = &cnt[batch << 5];
    float* outb    = out + batch * (NANG * NDET);
    const float B  = 128.499f;

    for (;;) {
        unsigned u = 0;
        if (lane == 0) u = atomicAdd(ctr, 1u);
        u = (unsigned)__builtin_amdgcn_readfirstlane((int)u);
        if (u >= (unsigned)NUB) break;

        int j = (int)(u / (unsigned)NANG);          // chunk order index 0..22
        int a = (int)(u - (unsigned)j * (unsigned)NANG);
        int ci = 11 + ((j + 1) >> 1) * ((j & 1) ? 1 : -1);  // center-out (longest first)
        int det0 = ci << 4;

        float ang = (float)a * 0.017453292519943295f;
        float si = __sinf(ang), co = __cosf(ang);
        float rsi = __builtin_amdgcn_rcpf(si);      // +inf only at a=0 (handled)
        float rco = __builtin_amdgcn_rcpf(co);      // co never exactly 0
        float nsi = -si;
        float dx64 = nsi * 64.f, dy64 = co * 64.f;

        // --- per-lane branchless setup for 16 rays (4 redundant copies) ---
        int det = det0 + (lane & 15);
        float s  = (float)det - 181.0f;
        float sx = s * co, sy = s * si;
        // x-slab: px = sx - t*si in [-B,B]
        float t1 = (sx - B) * rsi, t2 = (sx + B) * rsi;
        float tlo = fminf(t1, t2), thi = fmaxf(t1, t2);
        // y-slab: py = sy + t*co in [-B,B]
        float u1 = (-B - sy) * rco, u2 = (B - sy) * rco;
        tlo = fmaxf(tlo, fminf(u1, u2));
        thi = fminf(thi, fmaxf(u1, u2));
        tlo += 1e-3f; thi -= 1e-3f;                 // slab-only margin (OOB safety)
        // k window with saturation-proof integer clamps
        int k0 = (int)ceilf(tlo + 181.f);           // NaN/inf -> saturates, clamped below
        int k1 = (int)floorf(thi + 181.f);
        k0 = max(0, min(k0, 363));
        k1 = max(-1, min(k1, 362));
        int n = k1 - k0 + 1;
        if (det >= NDET) n = 0;
        n = max(n, 0);
        unsigned packv = ((unsigned)k0 & 0xFFFFu) | ((unsigned)n << 16);
        // local start coords at k=0: fx(k) = Ax + k*(-si), fy(k) = Ay + k*co
        float Ax = fmaf(181.f, si, sx) + 129.5f;    // px + 129.5 at k=0
        float Ay = fmaf(-181.f, co, sy) + 128.5f;   // py + 128.5 at k=0

        float myout = 0.f;
        for (int r = 0; r < DCH; ++r) {
            unsigned pk = (unsigned)__builtin_amdgcn_readlane((int)packv, r);
            int n_r = (int)(pk >> 16);
            if (n_r > 0) {
                int   k0r = (int)(pk & 0xFFFFu);
                float Axr = rlane_f(Ax, r), Ayr = rlane_f(Ay, r);
                float kf = (float)(k0r + lane);
                float fx = fmaf(kf, nsi, Axr);
                float fy = fmaf(kf, co,  Ayr);
                float acc = 0.f;
                int it = n_r >> 6, rem = n_r & 63;
                while (it >= 2) {                   // 2x unrolled for LDS ILP
                    float fxb = fx + dx64, fyb = fy + dy64;
                    acc += SAMP(fx, fy);
                    acc += SAMP(fxb, fyb);
                    fx = fxb + dx64; fy = fyb + dy64;
                    it -= 2;
                }
                if (it) { acc += SAMP(fx, fy); fx += dx64; fy += dy64; }
                if (lane < rem) acc += SAMP(fx, fy);
                for (int m = 32; m; m >>= 1) acc += __shfl_xor(acc, m);
                myout = (lane == r) ? acc : myout;
            }
        }
        if (lane < DCH) {
            int dd = det0 + lane;
            if (dd < NDET) outb[a * NDET + dd] = myout;
        }
    }
}

extern "C" void kernel_launch(void* const* d_in, const int* in_sizes, int n_in,
                              void* d_out, int out_size, void* d_ws, size_t ws_size,
                              hipStream_t stream) {
    const float* img = (const float*)d_in[0];
    float* out = (float*)d_out;
    unsigned* cnt = (unsigned*)d_ws;

    hipFuncSetAttribute((const void*)proj_kernel,
                        hipFuncAttributeMaxDynamicSharedMemorySize, (int)LDS_BYTES);
    hipMemsetAsync(d_ws, 0, 2 * 32 * sizeof(unsigned), stream);
    proj_kernel<<<256, 1024, LDS_BYTES, stream>>>(img, out, cnt);
}